// Round 17
// baseline (518.483 us; speedup 1.0000x reference)
//
#include <hip/hip_runtime.h>
#include <hip/hip_bf16.h>
#include <stdint.h>

#define NDIM 512
#define NN (NDIM*NDIM)      // 262144 positions
#define CDIM 128
#define LDSP 136            // padded LDS stride (f16 elems): 272B, 16B-mult

typedef __attribute__((ext_vector_type(8))) short short8;
typedef __attribute__((ext_vector_type(4))) short short4v;
typedef __attribute__((ext_vector_type(4))) float f32x4;
typedef __attribute__((ext_vector_type(8))) _Float16 half8;
typedef unsigned long long ull;

__device__ __forceinline__ unsigned short f2h(float f) {
    union { _Float16 h; unsigned short u; } v;
    v.h = (_Float16)f;
    return v.u;
}
__device__ __forceinline__ float h2f(unsigned short u) {
    union { _Float16 h; unsigned short u; } v;
    v.u = u;
    return (float)v.h;
}
__device__ __forceinline__ f32x4 mfma16(short8 a, short8 b, f32x4 c) {
    return __builtin_amdgcn_mfma_f32_16x16x32_f16(
        __builtin_bit_cast(half8, a), __builtin_bit_cast(half8, b), c, 0, 0, 0);
}
__device__ __forceinline__ void gl_lds16(const void* g, void* l) {
    __builtin_amdgcn_global_load_lds((const __attribute__((address_space(1))) void*)g,
                                     (__attribute__((address_space(3))) void*)l,
                                     16, 0, 0);
}

// ---------------- K0: weight prep --------------------------------------------
// Wfrag: 5 proj matrices in MFMA-fragment order (f16). Chunk idx = s*2048 +
// h*1024 + kk*256 + n*64 + lane; holds w_s[k0+e][col], col=h*64+n*16+(lane&15),
// k0=kk*32+(lane>>4)*8.  Wo_t[c][h] = w_o[h][c] (f16).
__global__ void k0_prep(const float* __restrict__ w_ag, const float* __restrict__ w_ap,
                        const float* __restrict__ w_bg, const float* __restrict__ w_bp,
                        const float* __restrict__ w_g,  const float* __restrict__ w_o,
                        unsigned short* __restrict__ Wfrag, unsigned short* __restrict__ Wo_t)
{
    int idx = blockIdx.x * 256 + threadIdx.x;
    if (idx < 10240) {
        int lane = idx & 63;
        int n  = (idx >> 6) & 3;
        int kk = (idx >> 8) & 3;
        int h  = (idx >> 10) & 1;
        int s  = idx >> 11;          // 0..4
        const float* w = (s==0) ? w_ag : (s==1) ? w_ap : (s==2) ? w_bg : (s==3) ? w_bp : w_g;
        int col = h*64 + n*16 + (lane & 15);
        int k0  = kk*32 + (lane >> 4)*8;
        short8 pk;
        #pragma unroll
        for (int e = 0; e < 8; e++)
            pk[e] = (short)f2h(w[(k0 + e)*128 + col]);
        *(short8*)(Wfrag + (size_t)idx*8) = pk;
    } else if (idx < 10240 + 16384) {
        int i2 = idx - 10240;
        int cc = i2 >> 7, hh = i2 & 127;
        Wo_t[i2] = f2h(w_o[hh*128 + cc]);
    }
}

// ---------------- K1a: LayerNorm only (z f32 -> zln f16) --------------------------
// Pure streaming, 2 threads/row, one barrier (LN weights). Memory-bound.
__global__ __launch_bounds__(256, 8) void k1a_ln(
    const float* __restrict__ z,
    const float* __restrict__ lnw, const float* __restrict__ lnb,
    unsigned short* __restrict__ zln)
{
    __shared__ float lnw_s[128];
    __shared__ float lnb_s[128];
    const int t = threadIdx.x;
    if (t < 128) { lnw_s[t] = lnw[t]; lnb_s[t] = lnb[t]; }
    const int tid2 = t >> 1, half = t & 1;
    const int pos = blockIdx.x * 128 + tid2;

    float v[64];
    float s0 = 0.f, s1 = 0.f;
    {
        const float* zr = z + (size_t)pos * CDIM + half * 64;
        #pragma unroll
        for (int i = 0; i < 16; i++) {
            float4 q = *(const float4*)(zr + i*4);
            v[i*4+0] = q.x; v[i*4+1] = q.y; v[i*4+2] = q.z; v[i*4+3] = q.w;
        }
        #pragma unroll
        for (int i = 0; i < 64; i++) { s0 += v[i]; s1 += v[i]*v[i]; }
        s0 += __shfl_xor(s0, 1);
        s1 += __shfl_xor(s1, 1);
    }
    __syncthreads();   // lnw_s/lnb_s ready
    {
        float m  = s0 * (1.f/128.f);
        float va = s1 * (1.f/128.f) - m*m;
        float rs = rsqrtf(va + 1e-5f);
        unsigned short* zo = zln + (size_t)pos*CDIM + half*64;
        #pragma unroll
        for (int i = 0; i < 8; i++) {
            short8 pk;
            #pragma unroll
            for (int j = 0; j < 8; j++) {
                int c = half*64 + i*8 + j;
                pk[j] = (short)f2h((v[i*8+j]-m)*rs*lnw_s[c] + lnb_s[c]);
            }
            *(short8*)(zo + i*8) = pk;
        }
    }
}

// ---------------- K1b: 4 gated projections — ZERO barriers, ZERO LDS -------------
// 256 threads / 4 waves per 64-row tile (4096 blocks). wave = pr*2 + hh.
// Each wave: preload weight frags for (sG,hh),(sP,hh) into regs (reused across
// both row bands), A-fragments read directly from global zln, epilogue with
// shfl_xor(16) write-combine. No __syncthreads anywhere -> waves free-run.
__global__ __launch_bounds__(256, 3) void k1b_proj(
    const unsigned short* __restrict__ zln,
    const float* __restrict__ mask,
    const unsigned short* __restrict__ Wfrag,
    const float* __restrict__ b_ag, const float* __restrict__ b_ap,
    const float* __restrict__ b_bg, const float* __restrict__ b_bp,
    unsigned short* __restrict__ a_t, unsigned short* __restrict__ b_t)
{
    const int t = threadIdx.x;
    const int pos0 = blockIdx.x * 64;
    const int wave = t >> 6, lane = t & 63;
    const int hh = wave & 1;                  // column half
    const int pr = wave >> 1;                 // 0 = a-pair, 1 = b-pair
    const int lr = lane & 15, lh = lane >> 4;
    const int sG = pr*2, sP = pr*2 + 1;       // s indices: a:(0,1)  b:(2,3)

    unsigned short* dstg = pr ? b_t : a_t;
    const float* bgp = pr ? b_bg : b_ag;
    const float* bpp = pr ? b_bp : b_ap;

    // preload weight fragments (32 x 16B, one vmcnt wait), reused for wl=0,1
    const unsigned short* wfl = Wfrag + (size_t)lane*8;
    const unsigned short* wfG = wfl + (size_t)(sG*2 + hh)*8192;
    const unsigned short* wfP = wfl + (size_t)(sP*2 + hh)*8192;
    short8 wG[16], wP[16];
    #pragma unroll
    for (int i = 0; i < 16; i++) {
        wG[i] = *(const short8*)(wfG + i*512);
        wP[i] = *(const short8*)(wfP + i*512);
    }

    const int odd = lh & 1;

    #pragma unroll
    for (int wl = 0; wl < 2; wl++) {
        const unsigned short* zbase = zln + (size_t)(pos0 + wl*32)*CDIM;
        f32x4 G[2][4], P[2][4];
        #pragma unroll
        for (int m = 0; m < 2; m++)
            #pragma unroll
            for (int n = 0; n < 4; n++) {
                f32x4 zz = {0.f,0.f,0.f,0.f};
                G[m][n] = zz; P[m][n] = zz;
            }
        #pragma unroll
        for (int kk = 0; kk < 4; kk++) {
            const int k0 = kk*32 + lh*8;
            short8 af0 = *(const short8*)(zbase + (size_t)lr*CDIM + k0);
            short8 af1 = *(const short8*)(zbase + (size_t)(16 + lr)*CDIM + k0);
            #pragma unroll
            for (int n = 0; n < 4; n++) {
                G[0][n] = mfma16(af0, wG[kk*4 + n], G[0][n]);
                G[1][n] = mfma16(af1, wG[kk*4 + n], G[1][n]);
                P[0][n] = mfma16(af0, wP[kk*4 + n], P[0][n]);
                P[1][n] = mfma16(af1, wP[kk*4 + n], P[1][n]);
            }
        }

        // epilogue (R12-proven mapping): mask/bias read direct from L2-hot arrays
        const int base = wl*32 + lh*4 + (odd ? 12 : 0);
        float m0[4], m1[4];
        #pragma unroll
        for (int r = 0; r < 4; r++) {
            m0[r] = mask[pos0 + wl*32 + lh*4 + r];
            m1[r] = mask[pos0 + wl*32 + 16 + lh*4 + r];
        }
        #pragma unroll
        for (int n = 0; n < 4; n++) {
            int col = hh*64 + n*16 + lr;
            float bgv = bgp[col];
            float bpv = bpp[col];
            union { short4v v; ull u; } p0, p1;
            #pragma unroll
            for (int r = 0; r < 4; r++) {
                float g0 = 1.f / (1.f + __expf(-(G[0][n][r] + bgv)));
                p0.v[r] = (short)f2h(m0[r] * g0 * (P[0][n][r] + bpv));
                float g1 = 1.f / (1.f + __expf(-(G[1][n][r] + bgv)));
                p1.v[r] = (short)f2h(m1[r] * g1 * (P[1][n][r] + bpv));
            }
            ull r0 = __shfl_xor(p0.u, 16);
            ull r1 = __shfl_xor(p1.u, 16);
            union { ull u[2]; short8 v; } outv;
            outv.u[0] = odd ? r1 : p0.u;   // rows base..base+3
            outv.u[1] = odd ? p1.u : r0;   // rows base+4..base+7
            *(short8*)(dstg + (size_t)col*NN + pos0 + base) = outv.v;
        }
    }
}

// ---------------- K2: per-channel einsum x[c] = A_c * B_c^T ----------------------
// 128x128 tile, linear gl_lds staging + both-sides XOR swizzle (rule #21).
// LDS-transpose epilogue for full-line x_t stores. (R15-exact, passing.)
#define K2_SMEM 34816
__global__ __launch_bounds__(256, 2) void k2_einsum(
    const unsigned short* __restrict__ a_t,
    const unsigned short* __restrict__ b_t,
    unsigned short* __restrict__ x_t)
{
    __shared__ char smem[K2_SMEM];   // As 16KB | Bs 16KB ; epilogue: 128 x 136 x 2B

    const int c  = blockIdx.y;
    const int ti = (blockIdx.x >> 2) * 128;
    const int tj = (blockIdx.x & 3) * 128;
    const int t = threadIdx.x;
    const int wave = t >> 6, lane = t & 63;
    const int lr = lane & 15, lh = lane >> 4;
    const int wm = wave >> 1, wn = wave & 1;

    unsigned short* As = (unsigned short*)smem;
    unsigned short* Bs = (unsigned short*)(smem + 16384);

    const unsigned short* Ag = a_t + (size_t)c*NN + (size_t)ti*NDIM;
    const unsigned short* Bg = b_t + (size_t)c*NN + (size_t)tj*NDIM;

    const int srow = wave*32 + (lane >> 3);              // staging row within tile
    const int scol = ((lane & 7)*8) ^ ((lane >> 3) << 3); // inverse-swizzled source col
    const int rsw  = (lr & 7) << 3;                       // read-side XOR (elems)

    f32x4 acc[4][4] = {};

    for (int k0 = 0; k0 < NDIM; k0 += 64) {
        __syncthreads();
        #pragma unroll
        for (int it = 0; it < 4; it++) {
            int r = srow + it*8;
            gl_lds16(Ag + (size_t)r*NDIM + k0 + scol, (void*)(As + (wave*32 + it*8)*64));
            gl_lds16(Bg + (size_t)r*NDIM + k0 + scol, (void*)(Bs + (wave*32 + it*8)*64));
        }
        asm volatile("s_waitcnt vmcnt(0)" ::: "memory");
        __syncthreads();
        #pragma unroll
        for (int kk = 0; kk < 2; kk++) {
            const int kof = (kk*32 + lh*8) ^ rsw;
            short8 af[4], bfr[4];
            #pragma unroll
            for (int m = 0; m < 4; m++)
                af[m] = *(const short8*)&As[(wm*64 + m*16 + lr)*64 + kof];
            #pragma unroll
            for (int n = 0; n < 4; n++)
                bfr[n] = *(const short8*)&Bs[(wn*64 + n*16 + lr)*64 + kof];
            #pragma unroll
            for (int m = 0; m < 4; m++)
                #pragma unroll
                for (int n = 0; n < 4; n++)
                    acc[m][n] = mfma16(af[m], bfr[n], acc[m][n]);
        }
    }
    __syncthreads();   // all As/Bs reads done before epilogue reuse

    // epilogue: acc -> LDS [row][col] (stride 136 elems, 16B-aligned), then
    // coalesced full-line stores to x_t.
    unsigned short* eb = (unsigned short*)smem;
    #pragma unroll
    for (int m = 0; m < 4; m++) {
        int row = wm*64 + m*16 + lh*4;
        #pragma unroll
        for (int n = 0; n < 4; n++) {
            int col = wn*64 + n*16 + lr;
            #pragma unroll
            for (int r = 0; r < 4; r++)
                eb[(row + r)*136 + col] = f2h(acc[m][n][r]);
        }
    }
    __syncthreads();
    {
        const int row = t >> 1, half = t & 1;
        unsigned short* dst = x_t + (size_t)c*NN + (size_t)(ti + row)*NDIM + tj + half*64;
        #pragma unroll
        for (int i = 0; i < 8; i++)
            *(short8*)(dst + i*8) = *(const short8*)(eb + row*136 + half*64 + i*8);
    }
}

// ---------------- K3: LN_out + out-proj + in-kernel gate GEMM (R15-exact) --------
__global__ __launch_bounds__(256, 2) void k3_out(
    const unsigned short* __restrict__ x_t,
    const unsigned short* __restrict__ zln,
    const unsigned short* __restrict__ Wfrag,
    const unsigned short* __restrict__ Wo_t,
    const float* __restrict__ lnw, const float* __restrict__ lnb,
    const float* __restrict__ b_o, const float* __restrict__ b_g,
    float* __restrict__ out)
{
    __shared__ unsigned short xb[128*LDSP];   // x tile [c][pos]; reused for Wo [col][k]
    __shared__ unsigned short zl[128*LDSP];   // LN'd x [pos][c]; reused for z_ln [pos][c]
    __shared__ float lnw_s[128];
    __shared__ float lnb_s[128];
    __shared__ float bo_s[128];
    __shared__ float bg_s[128];

    const int t = threadIdx.x;
    const int pos0 = blockIdx.x * 128;
    const int tid2 = t >> 1, half = t & 1;
    const int wave = t >> 6, lane = t & 63;
    const int lr = lane & 15, lh = lane >> 4;

    if (t < 128) {
        lnw_s[t] = lnw[t]; lnb_s[t] = lnb[t];
        bo_s[t] = b_o[t];  bg_s[t] = b_g[t];
    }

    // stage x tile: thread pair per channel row, coalesced
    {
        const unsigned short* src = x_t + (size_t)tid2*NN + pos0 + half*64;
        unsigned short* dst = xb + tid2*LDSP + half*64;
        #pragma unroll
        for (int i = 0; i < 8; i++)
            *(short8*)(dst + i*8) = *(const short8*)(src + i*8);
    }
    __syncthreads();

    // LN over c: 2 threads per pos
    {
        float v[64];
        float s0 = 0.f, s1 = 0.f;
        #pragma unroll
        for (int i = 0; i < 64; i++) {
            float x = h2f(xb[(half*64 + i)*LDSP + tid2]);
            v[i] = x; s0 += x; s1 += x*x;
        }
        s0 += __shfl_xor(s0, 1);
        s1 += __shfl_xor(s1, 1);
        float m  = s0 * (1.f/128.f);
        float va = s1 * (1.f/128.f) - m*m;
        float rs = rsqrtf(va + 1e-5f);
        #pragma unroll
        for (int i = 0; i < 64; i++) {
            int cc = half*64 + i;
            zl[tid2*LDSP + cc] = f2h((v[i]-m)*rs*lnw_s[cc] + lnb_s[cc]);
        }
    }
    __syncthreads();

    // Wo into xb (alias; xb dead now)
    {
        const unsigned short* src = Wo_t + ((size_t)tid2*128 + half*64);
        unsigned short* dst = xb + tid2*LDSP + half*64;
        #pragma unroll
        for (int i = 0; i < 8; i++)
            *(short8*)(dst + i*8) = *(const short8*)(src + i*8);
    }
    __syncthreads();

    const int rowA0 = (wave*32 + lr)*LDSP;
    const int rowA1 = (wave*32 + 16 + lr)*LDSP;

    // GEMM1: acc1 = LN(x) @ Wo
    f32x4 acc1[2][8];
    #pragma unroll
    for (int m = 0; m < 2; m++)
        #pragma unroll
        for (int n = 0; n < 8; n++) { f32x4 zz = {0.f,0.f,0.f,0.f}; acc1[m][n] = zz; }
    #pragma unroll
    for (int kk = 0; kk < 4; kk++) {
        const int k0 = kk*32 + lh*8;
        short8 af0 = *(const short8*)&zl[rowA0 + k0];
        short8 af1 = *(const short8*)&zl[rowA1 + k0];
        #pragma unroll
        for (int n = 0; n < 8; n++) {
            short8 bf = *(const short8*)&xb[(n*16 + lr)*LDSP + k0];
            acc1[0][n] = mfma16(af0, bf, acc1[0][n]);
            acc1[1][n] = mfma16(af1, bf, acc1[1][n]);
        }
    }
    __syncthreads();   // all zl reads done

    // z_ln tile into zl (same [pos][c] layout)
    {
        const unsigned short* src = zln + (size_t)(pos0 + tid2)*CDIM + half*64;
        unsigned short* dst = zl + tid2*LDSP + half*64;
        #pragma unroll
        for (int i = 0; i < 8; i++)
            *(short8*)(dst + i*8) = *(const short8*)(src + i*8);
    }
    __syncthreads();

    // GEMM2: acc2 = z_ln @ w_g (B-fragments streamed from Wfrag s=4, K1's pattern)
    f32x4 acc2[2][8];
    #pragma unroll
    for (int m = 0; m < 2; m++)
        #pragma unroll
        for (int n = 0; n < 8; n++) { f32x4 zz = {0.f,0.f,0.f,0.f}; acc2[m][n] = zz; }
    const unsigned short* wfl = Wfrag + (size_t)lane*8;
    #pragma unroll
    for (int h = 0; h < 2; h++) {
        const unsigned short* wf = wfl + (size_t)(8 + h)*8192;   // s=4
        #pragma unroll
        for (int st = 0; st < 2; st++) {
            short8 wbuf[8];
            #pragma unroll
            for (int i = 0; i < 8; i++)
                wbuf[i] = *(const short8*)(wf + (st*8 + i)*512);
            #pragma unroll
            for (int k2 = 0; k2 < 2; k2++) {
                const int kk = st*2 + k2;
                const int k0 = kk*32 + lh*8;
                short8 af0 = *(const short8*)&zl[rowA0 + k0];
                short8 af1 = *(const short8*)&zl[rowA1 + k0];
                #pragma unroll
                for (int n = 0; n < 4; n++) {
                    acc2[0][h*4+n] = mfma16(af0, wbuf[k2*4 + n], acc2[0][h*4+n]);
                    acc2[1][h*4+n] = mfma16(af1, wbuf[k2*4 + n], acc2[1][h*4+n]);
                }
            }
        }
    }

    // epilogue: g = sigmoid(acc2 + bg), out = g * (acc1 + bo)   (f32 path for g)
    #pragma unroll
    for (int m = 0; m < 2; m++) {
        int rb = wave*32 + m*16 + lh*4;
        #pragma unroll
        for (int n = 0; n < 8; n++) {
            int col = n*16 + lr;
            float bo = bo_s[col];
            float bg = bg_s[col];
            #pragma unroll
            for (int r = 0; r < 4; r++) {
                float gv = 1.f / (1.f + __expf(-(acc2[m][n][r] + bg)));
                out[(size_t)(pos0 + rb + r)*CDIM + col] = gv * (acc1[m][n][r] + bo);
            }
        }
    }
}

// ---------------- launcher -------------------------------------------------------
extern "C" void kernel_launch(void* const* d_in, const int* in_sizes, int n_in,
                              void* d_out, int out_size, void* d_ws, size_t ws_size,
                              hipStream_t stream) {
    const float* z        = (const float*)d_in[0];
    const float* mask     = (const float*)d_in[1];
    const float* ln_in_w  = (const float*)d_in[2];
    const float* ln_in_b  = (const float*)d_in[3];
    const float* w_ap     = (const float*)d_in[4];
    const float* b_ap     = (const float*)d_in[5];
    const float* w_ag     = (const float*)d_in[6];
    const float* b_ag     = (const float*)d_in[7];
    const float* w_bp     = (const float*)d_in[8];
    const float* b_bp     = (const float*)d_in[9];
    const float* w_bg     = (const float*)d_in[10];
    const float* b_bg     = (const float*)d_in[11];
    const float* ln_out_w = (const float*)d_in[12];
    const float* ln_out_b = (const float*)d_in[13];
    const float* w_o      = (const float*)d_in[14];
    const float* b_o      = (const float*)d_in[15];
    const float* w_g      = (const float*)d_in[16];
    const float* b_g      = (const float*)d_in[17];

    char* ws = (char*)d_ws;
    const size_t BUF = (size_t)NN * 128 * 2;      // 64 MB per f16 buffer
    unsigned short* a_t   = (unsigned short*)(ws);
    unsigned short* b_t   = (unsigned short*)(ws + BUF);
    unsigned short* zln   = (unsigned short*)(ws + 2*BUF);
    unsigned short* x_t   = (unsigned short*)(ws + 3*BUF);
    unsigned short* Wfrag = (unsigned short*)(ws + 4*BUF);
    unsigned short* Wo_t  = (unsigned short*)(ws + 4*BUF + (size_t)10240*8*2);

    k0_prep<<<104, 256, 0, stream>>>(w_ag, w_ap, w_bg, w_bp, w_g, w_o, Wfrag, Wo_t);
    k1a_ln<<<NN/128, 256, 0, stream>>>(z, ln_in_w, ln_in_b, zln);
    k1b_proj<<<NN/64, 256, 0, stream>>>(zln, mask, Wfrag,
                                        b_ag, b_ap, b_bg, b_bp, a_t, b_t);
    k2_einsum<<<dim3(16, 128), 256, 0, stream>>>(a_t, b_t, x_t);
    k3_out<<<NN/128, 256, 0, stream>>>(x_t, zln, Wfrag, Wo_t, ln_out_w, ln_out_b,
                                       b_o, b_g, (float*)d_out);
}

// Round 18
// 335.677 us; speedup vs baseline: 1.5446x; 1.5446x over previous
//
#include <hip/hip_runtime.h>
#include <hip/hip_bf16.h>
#include <stdint.h>

#define NDIM 512
#define NN (NDIM*NDIM)      // 262144 positions
#define CDIM 128
#define LDSP 136            // padded LDS stride (f16 elems): 272B, 16B-mult

typedef __attribute__((ext_vector_type(8))) short short8;
typedef __attribute__((ext_vector_type(4))) short short4v;
typedef __attribute__((ext_vector_type(4))) float f32x4;
typedef __attribute__((ext_vector_type(8))) _Float16 half8;
typedef unsigned long long ull;

__device__ __forceinline__ unsigned short f2h(float f) {
    union { _Float16 h; unsigned short u; } v;
    v.h = (_Float16)f;
    return v.u;
}
__device__ __forceinline__ float h2f(unsigned short u) {
    union { _Float16 h; unsigned short u; } v;
    v.u = u;
    return (float)v.h;
}
__device__ __forceinline__ f32x4 mfma16(short8 a, short8 b, f32x4 c) {
    return __builtin_amdgcn_mfma_f32_16x16x32_f16(
        __builtin_bit_cast(half8, a), __builtin_bit_cast(half8, b), c, 0, 0, 0);
}
__device__ __forceinline__ void gl_lds16(const void* g, void* l) {
    __builtin_amdgcn_global_load_lds((const __attribute__((address_space(1))) void*)g,
                                     (__attribute__((address_space(3))) void*)l,
                                     16, 0, 0);
}

// ---------------- K0: weight prep --------------------------------------------
// Wfrag: 5 proj matrices in MFMA-fragment order (f16). Chunk idx = s*2048 +
// h*1024 + kk*256 + n*64 + lane; holds w_s[k0+e][col], col=h*64+n*16+(lane&15),
// k0=kk*32+(lane>>4)*8.  Wo_t[c][h] = w_o[h][c] (f16).
__global__ void k0_prep(const float* __restrict__ w_ag, const float* __restrict__ w_ap,
                        const float* __restrict__ w_bg, const float* __restrict__ w_bp,
                        const float* __restrict__ w_g,  const float* __restrict__ w_o,
                        unsigned short* __restrict__ Wfrag, unsigned short* __restrict__ Wo_t)
{
    int idx = blockIdx.x * 256 + threadIdx.x;
    if (idx < 10240) {
        int lane = idx & 63;
        int n  = (idx >> 6) & 3;
        int kk = (idx >> 8) & 3;
        int h  = (idx >> 10) & 1;
        int s  = idx >> 11;          // 0..4
        const float* w = (s==0) ? w_ag : (s==1) ? w_ap : (s==2) ? w_bg : (s==3) ? w_bp : w_g;
        int col = h*64 + n*16 + (lane & 15);
        int k0  = kk*32 + (lane >> 4)*8;
        short8 pk;
        #pragma unroll
        for (int e = 0; e < 8; e++)
            pk[e] = (short)f2h(w[(k0 + e)*128 + col]);
        *(short8*)(Wfrag + (size_t)idx*8) = pk;
    } else if (idx < 10240 + 16384) {
        int i2 = idx - 10240;
        int cc = i2 >> 7, hh = i2 & 127;
        Wo_t[i2] = f2h(w_o[hh*128 + cc]);
    }
}

// ---------------- K1a: LayerNorm only (z f32 -> zln f16) --------------------------
// Pure streaming, 2 threads/row, one barrier (LN weights). Memory-bound.
__global__ __launch_bounds__(256, 8) void k1a_ln(
    const float* __restrict__ z,
    const float* __restrict__ lnw, const float* __restrict__ lnb,
    unsigned short* __restrict__ zln)
{
    __shared__ float lnw_s[128];
    __shared__ float lnb_s[128];
    const int t = threadIdx.x;
    if (t < 128) { lnw_s[t] = lnw[t]; lnb_s[t] = lnb[t]; }
    const int tid2 = t >> 1, half = t & 1;
    const int pos = blockIdx.x * 128 + tid2;

    float v[64];
    float s0 = 0.f, s1 = 0.f;
    {
        const float* zr = z + (size_t)pos * CDIM + half * 64;
        #pragma unroll
        for (int i = 0; i < 16; i++) {
            float4 q = *(const float4*)(zr + i*4);
            v[i*4+0] = q.x; v[i*4+1] = q.y; v[i*4+2] = q.z; v[i*4+3] = q.w;
        }
        #pragma unroll
        for (int i = 0; i < 64; i++) { s0 += v[i]; s1 += v[i]*v[i]; }
        s0 += __shfl_xor(s0, 1);
        s1 += __shfl_xor(s1, 1);
    }
    __syncthreads();   // lnw_s/lnb_s ready
    {
        float m  = s0 * (1.f/128.f);
        float va = s1 * (1.f/128.f) - m*m;
        float rs = rsqrtf(va + 1e-5f);
        unsigned short* zo = zln + (size_t)pos*CDIM + half*64;
        #pragma unroll
        for (int i = 0; i < 8; i++) {
            short8 pk;
            #pragma unroll
            for (int j = 0; j < 8; j++) {
                int c = half*64 + i*8 + j;
                pk[j] = (short)f2h((v[i*8+j]-m)*rs*lnw_s[c] + lnb_s[c]);
            }
            *(short8*)(zo + i*8) = pk;
        }
    }
}

// ---------------- K1b: 4 gated projections — zero barriers, zero LDS -------------
// 256 threads / 4 waves per 64-row tile (4096 blocks). wave = pr*2 + hh.
// SPILL FIX vs R17: weights staged 8-fragments-at-a-time (R12-proven register
// profile, VGPR~92) — G computed fully with wG, then P with wP; A-fragments
// re-read from L2-hot zln. Peak liveness ~110 < (256,2) cap 128 -> no scratch.
__global__ __launch_bounds__(256, 2) void k1b_proj(
    const unsigned short* __restrict__ zln,
    const float* __restrict__ mask,
    const unsigned short* __restrict__ Wfrag,
    const float* __restrict__ b_ag, const float* __restrict__ b_ap,
    const float* __restrict__ b_bg, const float* __restrict__ b_bp,
    unsigned short* __restrict__ a_t, unsigned short* __restrict__ b_t)
{
    const int t = threadIdx.x;
    const int pos0 = blockIdx.x * 64;
    const int wave = t >> 6, lane = t & 63;
    const int hh = wave & 1;                  // column half
    const int pr = wave >> 1;                 // 0 = a-pair, 1 = b-pair
    const int lr = lane & 15, lh = lane >> 4;
    const int sG = pr*2, sP = pr*2 + 1;       // s indices: a:(0,1)  b:(2,3)

    unsigned short* dstg = pr ? b_t : a_t;
    const float* bgp = pr ? b_bg : b_ag;
    const float* bpp = pr ? b_bp : b_ap;

    const unsigned short* wfl = Wfrag + (size_t)lane*8;
    const unsigned short* wfG = wfl + (size_t)(sG*2 + hh)*8192;
    const unsigned short* wfP = wfl + (size_t)(sP*2 + hh)*8192;
    const int odd = lh & 1;

    // staged GEMM (R12 gemmh pattern, A-frags from global zln)
    auto gemm = [&](const unsigned short* wf, const unsigned short* zbase,
                    f32x4 (&acc)[2][4]) {
        #pragma unroll
        for (int m = 0; m < 2; m++)
            #pragma unroll
            for (int n = 0; n < 4; n++) { f32x4 zz = {0.f,0.f,0.f,0.f}; acc[m][n] = zz; }
        #pragma unroll
        for (int st = 0; st < 2; st++) {
            short8 wbuf[8];
            #pragma unroll
            for (int i = 0; i < 8; i++)
                wbuf[i] = *(const short8*)(wf + (st*8 + i)*512);
            #pragma unroll
            for (int k2 = 0; k2 < 2; k2++) {
                const int kk = st*2 + k2;
                const int k0 = kk*32 + lh*8;
                short8 af0 = *(const short8*)(zbase + (size_t)lr*CDIM + k0);
                short8 af1 = *(const short8*)(zbase + (size_t)(16 + lr)*CDIM + k0);
                #pragma unroll
                for (int n = 0; n < 4; n++) {
                    acc[0][n] = mfma16(af0, wbuf[k2*4 + n], acc[0][n]);
                    acc[1][n] = mfma16(af1, wbuf[k2*4 + n], acc[1][n]);
                }
            }
        }
    };

    #pragma unroll
    for (int wl = 0; wl < 2; wl++) {
        const unsigned short* zbase = zln + (size_t)(pos0 + wl*32)*CDIM;
        f32x4 G[2][4], P[2][4];
        gemm(wfG, zbase, G);
        gemm(wfP, zbase, P);

        // epilogue (R12-proven mapping): shfl_xor(16) write-combine, full 64B
        // lines per (col, wl-band).
        const int base = wl*32 + lh*4 + (odd ? 12 : 0);
        float m0[4], m1[4];
        #pragma unroll
        for (int r = 0; r < 4; r++) {
            m0[r] = mask[pos0 + wl*32 + lh*4 + r];
            m1[r] = mask[pos0 + wl*32 + 16 + lh*4 + r];
        }
        #pragma unroll
        for (int n = 0; n < 4; n++) {
            int col = hh*64 + n*16 + lr;
            float bgv = bgp[col];
            float bpv = bpp[col];
            union { short4v v; ull u; } p0, p1;
            #pragma unroll
            for (int r = 0; r < 4; r++) {
                float g0 = 1.f / (1.f + __expf(-(G[0][n][r] + bgv)));
                p0.v[r] = (short)f2h(m0[r] * g0 * (P[0][n][r] + bpv));
                float g1 = 1.f / (1.f + __expf(-(G[1][n][r] + bgv)));
                p1.v[r] = (short)f2h(m1[r] * g1 * (P[1][n][r] + bpv));
            }
            ull r0 = __shfl_xor(p0.u, 16);
            ull r1 = __shfl_xor(p1.u, 16);
            union { ull u[2]; short8 v; } outv;
            outv.u[0] = odd ? r1 : p0.u;   // rows base..base+3
            outv.u[1] = odd ? p1.u : r0;   // rows base+4..base+7
            *(short8*)(dstg + (size_t)col*NN + pos0 + base) = outv.v;
        }
    }
}

// ---------------- K2: per-channel einsum x[c] = A_c * B_c^T ----------------------
// 128x128 tile, linear gl_lds staging + both-sides XOR swizzle (rule #21).
// LDS-transpose epilogue for full-line x_t stores. (R15-exact, passing.)
#define K2_SMEM 34816
__global__ __launch_bounds__(256, 2) void k2_einsum(
    const unsigned short* __restrict__ a_t,
    const unsigned short* __restrict__ b_t,
    unsigned short* __restrict__ x_t)
{
    __shared__ char smem[K2_SMEM];   // As 16KB | Bs 16KB ; epilogue: 128 x 136 x 2B

    const int c  = blockIdx.y;
    const int ti = (blockIdx.x >> 2) * 128;
    const int tj = (blockIdx.x & 3) * 128;
    const int t = threadIdx.x;
    const int wave = t >> 6, lane = t & 63;
    const int lr = lane & 15, lh = lane >> 4;
    const int wm = wave >> 1, wn = wave & 1;

    unsigned short* As = (unsigned short*)smem;
    unsigned short* Bs = (unsigned short*)(smem + 16384);

    const unsigned short* Ag = a_t + (size_t)c*NN + (size_t)ti*NDIM;
    const unsigned short* Bg = b_t + (size_t)c*NN + (size_t)tj*NDIM;

    const int srow = wave*32 + (lane >> 3);              // staging row within tile
    const int scol = ((lane & 7)*8) ^ ((lane >> 3) << 3); // inverse-swizzled source col
    const int rsw  = (lr & 7) << 3;                       // read-side XOR (elems)

    f32x4 acc[4][4] = {};

    for (int k0 = 0; k0 < NDIM; k0 += 64) {
        __syncthreads();
        #pragma unroll
        for (int it = 0; it < 4; it++) {
            int r = srow + it*8;
            gl_lds16(Ag + (size_t)r*NDIM + k0 + scol, (void*)(As + (wave*32 + it*8)*64));
            gl_lds16(Bg + (size_t)r*NDIM + k0 + scol, (void*)(Bs + (wave*32 + it*8)*64));
        }
        asm volatile("s_waitcnt vmcnt(0)" ::: "memory");
        __syncthreads();
        #pragma unroll
        for (int kk = 0; kk < 2; kk++) {
            const int kof = (kk*32 + lh*8) ^ rsw;
            short8 af[4], bfr[4];
            #pragma unroll
            for (int m = 0; m < 4; m++)
                af[m] = *(const short8*)&As[(wm*64 + m*16 + lr)*64 + kof];
            #pragma unroll
            for (int n = 0; n < 4; n++)
                bfr[n] = *(const short8*)&Bs[(wn*64 + n*16 + lr)*64 + kof];
            #pragma unroll
            for (int m = 0; m < 4; m++)
                #pragma unroll
                for (int n = 0; n < 4; n++)
                    acc[m][n] = mfma16(af[m], bfr[n], acc[m][n]);
        }
    }
    __syncthreads();   // all As/Bs reads done before epilogue reuse

    // epilogue: acc -> LDS [row][col] (stride 136 elems, 16B-aligned), then
    // coalesced full-line stores to x_t.
    unsigned short* eb = (unsigned short*)smem;
    #pragma unroll
    for (int m = 0; m < 4; m++) {
        int row = wm*64 + m*16 + lh*4;
        #pragma unroll
        for (int n = 0; n < 4; n++) {
            int col = wn*64 + n*16 + lr;
            #pragma unroll
            for (int r = 0; r < 4; r++)
                eb[(row + r)*136 + col] = f2h(acc[m][n][r]);
        }
    }
    __syncthreads();
    {
        const int row = t >> 1, half = t & 1;
        unsigned short* dst = x_t + (size_t)c*NN + (size_t)(ti + row)*NDIM + tj + half*64;
        #pragma unroll
        for (int i = 0; i < 8; i++)
            *(short8*)(dst + i*8) = *(const short8*)(eb + row*136 + half*64 + i*8);
    }
}

// ---------------- K3: LN_out + out-proj + in-kernel gate GEMM (R15-exact) --------
__global__ __launch_bounds__(256, 2) void k3_out(
    const unsigned short* __restrict__ x_t,
    const unsigned short* __restrict__ zln,
    const unsigned short* __restrict__ Wfrag,
    const unsigned short* __restrict__ Wo_t,
    const float* __restrict__ lnw, const float* __restrict__ lnb,
    const float* __restrict__ b_o, const float* __restrict__ b_g,
    float* __restrict__ out)
{
    __shared__ unsigned short xb[128*LDSP];   // x tile [c][pos]; reused for Wo [col][k]
    __shared__ unsigned short zl[128*LDSP];   // LN'd x [pos][c]; reused for z_ln [pos][c]
    __shared__ float lnw_s[128];
    __shared__ float lnb_s[128];
    __shared__ float bo_s[128];
    __shared__ float bg_s[128];

    const int t = threadIdx.x;
    const int pos0 = blockIdx.x * 128;
    const int tid2 = t >> 1, half = t & 1;
    const int wave = t >> 6, lane = t & 63;
    const int lr = lane & 15, lh = lane >> 4;

    if (t < 128) {
        lnw_s[t] = lnw[t]; lnb_s[t] = lnb[t];
        bo_s[t] = b_o[t];  bg_s[t] = b_g[t];
    }

    // stage x tile: thread pair per channel row, coalesced
    {
        const unsigned short* src = x_t + (size_t)tid2*NN + pos0 + half*64;
        unsigned short* dst = xb + tid2*LDSP + half*64;
        #pragma unroll
        for (int i = 0; i < 8; i++)
            *(short8*)(dst + i*8) = *(const short8*)(src + i*8);
    }
    __syncthreads();

    // LN over c: 2 threads per pos
    {
        float v[64];
        float s0 = 0.f, s1 = 0.f;
        #pragma unroll
        for (int i = 0; i < 64; i++) {
            float x = h2f(xb[(half*64 + i)*LDSP + tid2]);
            v[i] = x; s0 += x; s1 += x*x;
        }
        s0 += __shfl_xor(s0, 1);
        s1 += __shfl_xor(s1, 1);
        float m  = s0 * (1.f/128.f);
        float va = s1 * (1.f/128.f) - m*m;
        float rs = rsqrtf(va + 1e-5f);
        #pragma unroll
        for (int i = 0; i < 64; i++) {
            int cc = half*64 + i;
            zl[tid2*LDSP + cc] = f2h((v[i]-m)*rs*lnw_s[cc] + lnb_s[cc]);
        }
    }
    __syncthreads();

    // Wo into xb (alias; xb dead now)
    {
        const unsigned short* src = Wo_t + ((size_t)tid2*128 + half*64);
        unsigned short* dst = xb + tid2*LDSP + half*64;
        #pragma unroll
        for (int i = 0; i < 8; i++)
            *(short8*)(dst + i*8) = *(const short8*)(src + i*8);
    }
    __syncthreads();

    const int rowA0 = (wave*32 + lr)*LDSP;
    const int rowA1 = (wave*32 + 16 + lr)*LDSP;

    // GEMM1: acc1 = LN(x) @ Wo
    f32x4 acc1[2][8];
    #pragma unroll
    for (int m = 0; m < 2; m++)
        #pragma unroll
        for (int n = 0; n < 8; n++) { f32x4 zz = {0.f,0.f,0.f,0.f}; acc1[m][n] = zz; }
    #pragma unroll
    for (int kk = 0; kk < 4; kk++) {
        const int k0 = kk*32 + lh*8;
        short8 af0 = *(const short8*)&zl[rowA0 + k0];
        short8 af1 = *(const short8*)&zl[rowA1 + k0];
        #pragma unroll
        for (int n = 0; n < 8; n++) {
            short8 bf = *(const short8*)&xb[(n*16 + lr)*LDSP + k0];
            acc1[0][n] = mfma16(af0, bf, acc1[0][n]);
            acc1[1][n] = mfma16(af1, bf, acc1[1][n]);
        }
    }
    __syncthreads();   // all zl reads done

    // z_ln tile into zl (same [pos][c] layout)
    {
        const unsigned short* src = zln + (size_t)(pos0 + tid2)*CDIM + half*64;
        unsigned short* dst = zl + tid2*LDSP + half*64;
        #pragma unroll
        for (int i = 0; i < 8; i++)
            *(short8*)(dst + i*8) = *(const short8*)(src + i*8);
    }
    __syncthreads();

    // GEMM2: acc2 = z_ln @ w_g (B-fragments streamed from Wfrag s=4, K1's pattern)
    f32x4 acc2[2][8];
    #pragma unroll
    for (int m = 0; m < 2; m++)
        #pragma unroll
        for (int n = 0; n < 8; n++) { f32x4 zz = {0.f,0.f,0.f,0.f}; acc2[m][n] = zz; }
    const unsigned short* wfl = Wfrag + (size_t)lane*8;
    #pragma unroll
    for (int h = 0; h < 2; h++) {
        const unsigned short* wf = wfl + (size_t)(8 + h)*8192;   // s=4
        #pragma unroll
        for (int st = 0; st < 2; st++) {
            short8 wbuf[8];
            #pragma unroll
            for (int i = 0; i < 8; i++)
                wbuf[i] = *(const short8*)(wf + (st*8 + i)*512);
            #pragma unroll
            for (int k2 = 0; k2 < 2; k2++) {
                const int kk = st*2 + k2;
                const int k0 = kk*32 + lh*8;
                short8 af0 = *(const short8*)&zl[rowA0 + k0];
                short8 af1 = *(const short8*)&zl[rowA1 + k0];
                #pragma unroll
                for (int n = 0; n < 4; n++) {
                    acc2[0][h*4+n] = mfma16(af0, wbuf[k2*4 + n], acc2[0][h*4+n]);
                    acc2[1][h*4+n] = mfma16(af1, wbuf[k2*4 + n], acc2[1][h*4+n]);
                }
            }
        }
    }

    // epilogue: g = sigmoid(acc2 + bg), out = g * (acc1 + bo)   (f32 path for g)
    #pragma unroll
    for (int m = 0; m < 2; m++) {
        int rb = wave*32 + m*16 + lh*4;
        #pragma unroll
        for (int n = 0; n < 8; n++) {
            int col = n*16 + lr;
            float bo = bo_s[col];
            float bg = bg_s[col];
            #pragma unroll
            for (int r = 0; r < 4; r++) {
                float gv = 1.f / (1.f + __expf(-(acc2[m][n][r] + bg)));
                out[(size_t)(pos0 + rb + r)*CDIM + col] = gv * (acc1[m][n][r] + bo);
            }
        }
    }
}

// ---------------- launcher -------------------------------------------------------
extern "C" void kernel_launch(void* const* d_in, const int* in_sizes, int n_in,
                              void* d_out, int out_size, void* d_ws, size_t ws_size,
                              hipStream_t stream) {
    const float* z        = (const float*)d_in[0];
    const float* mask     = (const float*)d_in[1];
    const float* ln_in_w  = (const float*)d_in[2];
    const float* ln_in_b  = (const float*)d_in[3];
    const float* w_ap     = (const float*)d_in[4];
    const float* b_ap     = (const float*)d_in[5];
    const float* w_ag     = (const float*)d_in[6];
    const float* b_ag     = (const float*)d_in[7];
    const float* w_bp     = (const float*)d_in[8];
    const float* b_bp     = (const float*)d_in[9];
    const float* w_bg     = (const float*)d_in[10];
    const float* b_bg     = (const float*)d_in[11];
    const float* ln_out_w = (const float*)d_in[12];
    const float* ln_out_b = (const float*)d_in[13];
    const float* w_o      = (const float*)d_in[14];
    const float* b_o      = (const float*)d_in[15];
    const float* w_g      = (const float*)d_in[16];
    const float* b_g      = (const float*)d_in[17];

    char* ws = (char*)d_ws;
    const size_t BUF = (size_t)NN * 128 * 2;      // 64 MB per f16 buffer
    unsigned short* a_t   = (unsigned short*)(ws);
    unsigned short* b_t   = (unsigned short*)(ws + BUF);
    unsigned short* zln   = (unsigned short*)(ws + 2*BUF);
    unsigned short* x_t   = (unsigned short*)(ws + 3*BUF);
    unsigned short* Wfrag = (unsigned short*)(ws + 4*BUF);
    unsigned short* Wo_t  = (unsigned short*)(ws + 4*BUF + (size_t)10240*8*2);

    k0_prep<<<104, 256, 0, stream>>>(w_ag, w_ap, w_bg, w_bp, w_g, w_o, Wfrag, Wo_t);
    k1a_ln<<<NN/128, 256, 0, stream>>>(z, ln_in_w, ln_in_b, zln);
    k1b_proj<<<NN/64, 256, 0, stream>>>(zln, mask, Wfrag,
                                        b_ag, b_ap, b_bg, b_bp, a_t, b_t);
    k2_einsum<<<dim3(16, 128), 256, 0, stream>>>(a_t, b_t, x_t);
    k3_out<<<NN/128, 256, 0, stream>>>(x_t, zln, Wfrag, Wo_t, ln_out_w, ln_out_b,
                                       b_o, b_g, (float*)d_out);
}

// Round 19
// 292.118 us; speedup vs baseline: 1.7749x; 1.1491x over previous
//
#include <hip/hip_runtime.h>
#include <hip/hip_bf16.h>
#include <stdint.h>

#define NDIM 512
#define NN (NDIM*NDIM)      // 262144 positions
#define CDIM 128
#define LDSP 136            // padded LDS stride (f16 elems): 272B, 16B-mult

typedef __attribute__((ext_vector_type(8))) short short8;
typedef __attribute__((ext_vector_type(4))) short short4v;
typedef __attribute__((ext_vector_type(4))) float f32x4;
typedef __attribute__((ext_vector_type(8))) _Float16 half8;
typedef unsigned long long ull;

__device__ __forceinline__ unsigned short f2h(float f) {
    union { _Float16 h; unsigned short u; } v;
    v.h = (_Float16)f;
    return v.u;
}
__device__ __forceinline__ float h2f(unsigned short u) {
    union { _Float16 h; unsigned short u; } v;
    v.u = u;
    return (float)v.h;
}
__device__ __forceinline__ f32x4 mfma16(short8 a, short8 b, f32x4 c) {
    return __builtin_amdgcn_mfma_f32_16x16x32_f16(
        __builtin_bit_cast(half8, a), __builtin_bit_cast(half8, b), c, 0, 0, 0);
}
__device__ __forceinline__ void gl_lds16(const void* g, void* l) {
    __builtin_amdgcn_global_load_lds((const __attribute__((address_space(1))) void*)g,
                                     (__attribute__((address_space(3))) void*)l,
                                     16, 0, 0);
}

// ---------------- K0: weight prep --------------------------------------------
// Wfrag: 5 proj matrices in MFMA-fragment order (f16). Chunk idx = s*2048 +
// h*1024 + kk*256 + n*64 + lane; holds w_s[k0+e][col], col=h*64+n*16+(lane&15),
// k0=kk*32+(lane>>4)*8.  Wo_t[c][h] = w_o[h][c] (f16).
__global__ void k0_prep(const float* __restrict__ w_ag, const float* __restrict__ w_ap,
                        const float* __restrict__ w_bg, const float* __restrict__ w_bp,
                        const float* __restrict__ w_g,  const float* __restrict__ w_o,
                        unsigned short* __restrict__ Wfrag, unsigned short* __restrict__ Wo_t)
{
    int idx = blockIdx.x * 256 + threadIdx.x;
    if (idx < 10240) {
        int lane = idx & 63;
        int n  = (idx >> 6) & 3;
        int kk = (idx >> 8) & 3;
        int h  = (idx >> 10) & 1;
        int s  = idx >> 11;          // 0..4
        const float* w = (s==0) ? w_ag : (s==1) ? w_ap : (s==2) ? w_bg : (s==3) ? w_bp : w_g;
        int col = h*64 + n*16 + (lane & 15);
        int k0  = kk*32 + (lane >> 4)*8;
        short8 pk;
        #pragma unroll
        for (int e = 0; e < 8; e++)
            pk[e] = (short)f2h(w[(k0 + e)*128 + col]);
        *(short8*)(Wfrag + (size_t)idx*8) = pk;
    } else if (idx < 10240 + 16384) {
        int i2 = idx - 10240;
        int cc = i2 >> 7, hh = i2 & 127;
        Wo_t[i2] = f2h(w_o[hh*128 + cc]);
    }
}

// ---------------- K1a: LayerNorm only (z f32 -> zln f16) --------------------------
// SPILL FIX vs R18: 4 threads/row (v[32], ~50 regs peak) so the (256,8)-implied
// 64-VGPR cap holds WITHOUT scratch. 64 rows/block, 4096 blocks, max occupancy.
__global__ __launch_bounds__(256, 8) void k1a_ln(
    const float* __restrict__ z,
    const float* __restrict__ lnw, const float* __restrict__ lnb,
    unsigned short* __restrict__ zln)
{
    __shared__ float lnw_s[128];
    __shared__ float lnb_s[128];
    const int t = threadIdx.x;
    if (t < 128) { lnw_s[t] = lnw[t]; lnb_s[t] = lnb[t]; }
    const int row4 = t >> 2, q = t & 3;
    const int pos = blockIdx.x * 64 + row4;

    float v[32];
    float s0 = 0.f, s1 = 0.f;
    {
        const float* zr = z + (size_t)pos * CDIM + q * 32;
        #pragma unroll
        for (int i = 0; i < 8; i++) {
            float4 qv = *(const float4*)(zr + i*4);
            v[i*4+0] = qv.x; v[i*4+1] = qv.y; v[i*4+2] = qv.z; v[i*4+3] = qv.w;
        }
        #pragma unroll
        for (int i = 0; i < 32; i++) { s0 += v[i]; s1 += v[i]*v[i]; }
        s0 += __shfl_xor(s0, 1);
        s1 += __shfl_xor(s1, 1);
        s0 += __shfl_xor(s0, 2);
        s1 += __shfl_xor(s1, 2);
    }
    __syncthreads();   // lnw_s/lnb_s ready
    {
        float m  = s0 * (1.f/128.f);
        float va = s1 * (1.f/128.f) - m*m;
        float rs = rsqrtf(va + 1e-5f);
        unsigned short* zo = zln + (size_t)pos*CDIM + q*32;
        #pragma unroll
        for (int i = 0; i < 4; i++) {
            short8 pk;
            #pragma unroll
            for (int j = 0; j < 8; j++) {
                int c = q*32 + i*8 + j;
                pk[j] = (short)f2h((v[i*8+j]-m)*rs*lnw_s[c] + lnb_s[c]);
            }
            *(short8*)(zo + i*8) = pk;
        }
    }
}

// ---------------- K1b: 4 gated projections — zero barriers, zero LDS -------------
// (R18-exact, 120us proven, no spill.) 256 threads / 4 waves per 64-row tile.
// wave = pr*2 + hh. Weights staged 8-fragments-at-a-time; A-frags from L2-hot zln.
__global__ __launch_bounds__(256, 2) void k1b_proj(
    const unsigned short* __restrict__ zln,
    const float* __restrict__ mask,
    const unsigned short* __restrict__ Wfrag,
    const float* __restrict__ b_ag, const float* __restrict__ b_ap,
    const float* __restrict__ b_bg, const float* __restrict__ b_bp,
    unsigned short* __restrict__ a_t, unsigned short* __restrict__ b_t)
{
    const int t = threadIdx.x;
    const int pos0 = blockIdx.x * 64;
    const int wave = t >> 6, lane = t & 63;
    const int hh = wave & 1;                  // column half
    const int pr = wave >> 1;                 // 0 = a-pair, 1 = b-pair
    const int lr = lane & 15, lh = lane >> 4;
    const int sG = pr*2, sP = pr*2 + 1;       // s indices: a:(0,1)  b:(2,3)

    unsigned short* dstg = pr ? b_t : a_t;
    const float* bgp = pr ? b_bg : b_ag;
    const float* bpp = pr ? b_bp : b_ap;

    const unsigned short* wfl = Wfrag + (size_t)lane*8;
    const unsigned short* wfG = wfl + (size_t)(sG*2 + hh)*8192;
    const unsigned short* wfP = wfl + (size_t)(sP*2 + hh)*8192;
    const int odd = lh & 1;

    // staged GEMM (R12 gemmh pattern, A-frags from global zln)
    auto gemm = [&](const unsigned short* wf, const unsigned short* zbase,
                    f32x4 (&acc)[2][4]) {
        #pragma unroll
        for (int m = 0; m < 2; m++)
            #pragma unroll
            for (int n = 0; n < 4; n++) { f32x4 zz = {0.f,0.f,0.f,0.f}; acc[m][n] = zz; }
        #pragma unroll
        for (int st = 0; st < 2; st++) {
            short8 wbuf[8];
            #pragma unroll
            for (int i = 0; i < 8; i++)
                wbuf[i] = *(const short8*)(wf + (st*8 + i)*512);
            #pragma unroll
            for (int k2 = 0; k2 < 2; k2++) {
                const int kk = st*2 + k2;
                const int k0 = kk*32 + lh*8;
                short8 af0 = *(const short8*)(zbase + (size_t)lr*CDIM + k0);
                short8 af1 = *(const short8*)(zbase + (size_t)(16 + lr)*CDIM + k0);
                #pragma unroll
                for (int n = 0; n < 4; n++) {
                    acc[0][n] = mfma16(af0, wbuf[k2*4 + n], acc[0][n]);
                    acc[1][n] = mfma16(af1, wbuf[k2*4 + n], acc[1][n]);
                }
            }
        }
    };

    #pragma unroll
    for (int wl = 0; wl < 2; wl++) {
        const unsigned short* zbase = zln + (size_t)(pos0 + wl*32)*CDIM;
        f32x4 G[2][4], P[2][4];
        gemm(wfG, zbase, G);
        gemm(wfP, zbase, P);

        // epilogue (R12-proven mapping): shfl_xor(16) write-combine, full 64B
        // lines per (col, wl-band).
        const int base = wl*32 + lh*4 + (odd ? 12 : 0);
        float m0[4], m1[4];
        #pragma unroll
        for (int r = 0; r < 4; r++) {
            m0[r] = mask[pos0 + wl*32 + lh*4 + r];
            m1[r] = mask[pos0 + wl*32 + 16 + lh*4 + r];
        }
        #pragma unroll
        for (int n = 0; n < 4; n++) {
            int col = hh*64 + n*16 + lr;
            float bgv = bgp[col];
            float bpv = bpp[col];
            union { short4v v; ull u; } p0, p1;
            #pragma unroll
            for (int r = 0; r < 4; r++) {
                float g0 = 1.f / (1.f + __expf(-(G[0][n][r] + bgv)));
                p0.v[r] = (short)f2h(m0[r] * g0 * (P[0][n][r] + bpv));
                float g1 = 1.f / (1.f + __expf(-(G[1][n][r] + bgv)));
                p1.v[r] = (short)f2h(m1[r] * g1 * (P[1][n][r] + bpv));
            }
            ull r0 = __shfl_xor(p0.u, 16);
            ull r1 = __shfl_xor(p1.u, 16);
            union { ull u[2]; short8 v; } outv;
            outv.u[0] = odd ? r1 : p0.u;   // rows base..base+3
            outv.u[1] = odd ? p1.u : r0;   // rows base+4..base+7
            *(short8*)(dstg + (size_t)col*NN + pos0 + base) = outv.v;
        }
    }
}

// ---------------- K2: per-channel einsum x[c] = A_c * B_c^T ----------------------
// 128x128 tile, linear gl_lds staging + both-sides XOR swizzle (rule #21).
// LDS-transpose epilogue for full-line x_t stores. (R15/R18-exact, passing.)
#define K2_SMEM 34816
__global__ __launch_bounds__(256, 2) void k2_einsum(
    const unsigned short* __restrict__ a_t,
    const unsigned short* __restrict__ b_t,
    unsigned short* __restrict__ x_t)
{
    __shared__ char smem[K2_SMEM];   // As 16KB | Bs 16KB ; epilogue: 128 x 136 x 2B

    const int c  = blockIdx.y;
    const int ti = (blockIdx.x >> 2) * 128;
    const int tj = (blockIdx.x & 3) * 128;
    const int t = threadIdx.x;
    const int wave = t >> 6, lane = t & 63;
    const int lr = lane & 15, lh = lane >> 4;
    const int wm = wave >> 1, wn = wave & 1;

    unsigned short* As = (unsigned short*)smem;
    unsigned short* Bs = (unsigned short*)(smem + 16384);

    const unsigned short* Ag = a_t + (size_t)c*NN + (size_t)ti*NDIM;
    const unsigned short* Bg = b_t + (size_t)c*NN + (size_t)tj*NDIM;

    const int srow = wave*32 + (lane >> 3);              // staging row within tile
    const int scol = ((lane & 7)*8) ^ ((lane >> 3) << 3); // inverse-swizzled source col
    const int rsw  = (lr & 7) << 3;                       // read-side XOR (elems)

    f32x4 acc[4][4] = {};

    for (int k0 = 0; k0 < NDIM; k0 += 64) {
        __syncthreads();
        #pragma unroll
        for (int it = 0; it < 4; it++) {
            int r = srow + it*8;
            gl_lds16(Ag + (size_t)r*NDIM + k0 + scol, (void*)(As + (wave*32 + it*8)*64));
            gl_lds16(Bg + (size_t)r*NDIM + k0 + scol, (void*)(Bs + (wave*32 + it*8)*64));
        }
        asm volatile("s_waitcnt vmcnt(0)" ::: "memory");
        __syncthreads();
        #pragma unroll
        for (int kk = 0; kk < 2; kk++) {
            const int kof = (kk*32 + lh*8) ^ rsw;
            short8 af[4], bfr[4];
            #pragma unroll
            for (int m = 0; m < 4; m++)
                af[m] = *(const short8*)&As[(wm*64 + m*16 + lr)*64 + kof];
            #pragma unroll
            for (int n = 0; n < 4; n++)
                bfr[n] = *(const short8*)&Bs[(wn*64 + n*16 + lr)*64 + kof];
            #pragma unroll
            for (int m = 0; m < 4; m++)
                #pragma unroll
                for (int n = 0; n < 4; n++)
                    acc[m][n] = mfma16(af[m], bfr[n], acc[m][n]);
        }
    }
    __syncthreads();   // all As/Bs reads done before epilogue reuse

    // epilogue: acc -> LDS [row][col] (stride 136 elems, 16B-aligned), then
    // coalesced full-line stores to x_t.
    unsigned short* eb = (unsigned short*)smem;
    #pragma unroll
    for (int m = 0; m < 4; m++) {
        int row = wm*64 + m*16 + lh*4;
        #pragma unroll
        for (int n = 0; n < 4; n++) {
            int col = wn*64 + n*16 + lr;
            #pragma unroll
            for (int r = 0; r < 4; r++)
                eb[(row + r)*136 + col] = f2h(acc[m][n][r]);
        }
    }
    __syncthreads();
    {
        const int row = t >> 1, half = t & 1;
        unsigned short* dst = x_t + (size_t)c*NN + (size_t)(ti + row)*NDIM + tj + half*64;
        #pragma unroll
        for (int i = 0; i < 8; i++)
            *(short8*)(dst + i*8) = *(const short8*)(eb + row*136 + half*64 + i*8);
    }
}

// ---------------- K3: LN_out + out-proj + in-kernel gate GEMM (R18-exact) --------
__global__ __launch_bounds__(256, 2) void k3_out(
    const unsigned short* __restrict__ x_t,
    const unsigned short* __restrict__ zln,
    const unsigned short* __restrict__ Wfrag,
    const unsigned short* __restrict__ Wo_t,
    const float* __restrict__ lnw, const float* __restrict__ lnb,
    const float* __restrict__ b_o, const float* __restrict__ b_g,
    float* __restrict__ out)
{
    __shared__ unsigned short xb[128*LDSP];   // x tile [c][pos]; reused for Wo [col][k]
    __shared__ unsigned short zl[128*LDSP];   // LN'd x [pos][c]; reused for z_ln [pos][c]
    __shared__ float lnw_s[128];
    __shared__ float lnb_s[128];
    __shared__ float bo_s[128];
    __shared__ float bg_s[128];

    const int t = threadIdx.x;
    const int pos0 = blockIdx.x * 128;
    const int tid2 = t >> 1, half = t & 1;
    const int wave = t >> 6, lane = t & 63;
    const int lr = lane & 15, lh = lane >> 4;

    if (t < 128) {
        lnw_s[t] = lnw[t]; lnb_s[t] = lnb[t];
        bo_s[t] = b_o[t];  bg_s[t] = b_g[t];
    }

    // stage x tile: thread pair per channel row, coalesced
    {
        const unsigned short* src = x_t + (size_t)tid2*NN + pos0 + half*64;
        unsigned short* dst = xb + tid2*LDSP + half*64;
        #pragma unroll
        for (int i = 0; i < 8; i++)
            *(short8*)(dst + i*8) = *(const short8*)(src + i*8);
    }
    __syncthreads();

    // LN over c: 2 threads per pos
    {
        float v[64];
        float s0 = 0.f, s1 = 0.f;
        #pragma unroll
        for (int i = 0; i < 64; i++) {
            float x = h2f(xb[(half*64 + i)*LDSP + tid2]);
            v[i] = x; s0 += x; s1 += x*x;
        }
        s0 += __shfl_xor(s0, 1);
        s1 += __shfl_xor(s1, 1);
        float m  = s0 * (1.f/128.f);
        float va = s1 * (1.f/128.f) - m*m;
        float rs = rsqrtf(va + 1e-5f);
        #pragma unroll
        for (int i = 0; i < 64; i++) {
            int cc = half*64 + i;
            zl[tid2*LDSP + cc] = f2h((v[i]-m)*rs*lnw_s[cc] + lnb_s[cc]);
        }
    }
    __syncthreads();

    // Wo into xb (alias; xb dead now)
    {
        const unsigned short* src = Wo_t + ((size_t)tid2*128 + half*64);
        unsigned short* dst = xb + tid2*LDSP + half*64;
        #pragma unroll
        for (int i = 0; i < 8; i++)
            *(short8*)(dst + i*8) = *(const short8*)(src + i*8);
    }
    __syncthreads();

    const int rowA0 = (wave*32 + lr)*LDSP;
    const int rowA1 = (wave*32 + 16 + lr)*LDSP;

    // GEMM1: acc1 = LN(x) @ Wo
    f32x4 acc1[2][8];
    #pragma unroll
    for (int m = 0; m < 2; m++)
        #pragma unroll
        for (int n = 0; n < 8; n++) { f32x4 zz = {0.f,0.f,0.f,0.f}; acc1[m][n] = zz; }
    #pragma unroll
    for (int kk = 0; kk < 4; kk++) {
        const int k0 = kk*32 + lh*8;
        short8 af0 = *(const short8*)&zl[rowA0 + k0];
        short8 af1 = *(const short8*)&zl[rowA1 + k0];
        #pragma unroll
        for (int n = 0; n < 8; n++) {
            short8 bf = *(const short8*)&xb[(n*16 + lr)*LDSP + k0];
            acc1[0][n] = mfma16(af0, bf, acc1[0][n]);
            acc1[1][n] = mfma16(af1, bf, acc1[1][n]);
        }
    }
    __syncthreads();   // all zl reads done

    // z_ln tile into zl (same [pos][c] layout)
    {
        const unsigned short* src = zln + (size_t)(pos0 + tid2)*CDIM + half*64;
        unsigned short* dst = zl + tid2*LDSP + half*64;
        #pragma unroll
        for (int i = 0; i < 8; i++)
            *(short8*)(dst + i*8) = *(const short8*)(src + i*8);
    }
    __syncthreads();

    // GEMM2: acc2 = z_ln @ w_g (B-fragments streamed from Wfrag s=4, K1's pattern)
    f32x4 acc2[2][8];
    #pragma unroll
    for (int m = 0; m < 2; m++)
        #pragma unroll
        for (int n = 0; n < 8; n++) { f32x4 zz = {0.f,0.f,0.f,0.f}; acc2[m][n] = zz; }
    const unsigned short* wfl = Wfrag + (size_t)lane*8;
    #pragma unroll
    for (int h = 0; h < 2; h++) {
        const unsigned short* wf = wfl + (size_t)(8 + h)*8192;   // s=4
        #pragma unroll
        for (int st = 0; st < 2; st++) {
            short8 wbuf[8];
            #pragma unroll
            for (int i = 0; i < 8; i++)
                wbuf[i] = *(const short8*)(wf + (st*8 + i)*512);
            #pragma unroll
            for (int k2 = 0; k2 < 2; k2++) {
                const int kk = st*2 + k2;
                const int k0 = kk*32 + lh*8;
                short8 af0 = *(const short8*)&zl[rowA0 + k0];
                short8 af1 = *(const short8*)&zl[rowA1 + k0];
                #pragma unroll
                for (int n = 0; n < 4; n++) {
                    acc2[0][h*4+n] = mfma16(af0, wbuf[k2*4 + n], acc2[0][h*4+n]);
                    acc2[1][h*4+n] = mfma16(af1, wbuf[k2*4 + n], acc2[1][h*4+n]);
                }
            }
        }
    }

    // epilogue: g = sigmoid(acc2 + bg), out = g * (acc1 + bo)   (f32 path for g)
    #pragma unroll
    for (int m = 0; m < 2; m++) {
        int rb = wave*32 + m*16 + lh*4;
        #pragma unroll
        for (int n = 0; n < 8; n++) {
            int col = n*16 + lr;
            float bo = bo_s[col];
            float bg = bg_s[col];
            #pragma unroll
            for (int r = 0; r < 4; r++) {
                float gv = 1.f / (1.f + __expf(-(acc2[m][n][r] + bg)));
                out[(size_t)(pos0 + rb + r)*CDIM + col] = gv * (acc1[m][n][r] + bo);
            }
        }
    }
}

// ---------------- launcher -------------------------------------------------------
extern "C" void kernel_launch(void* const* d_in, const int* in_sizes, int n_in,
                              void* d_out, int out_size, void* d_ws, size_t ws_size,
                              hipStream_t stream) {
    const float* z        = (const float*)d_in[0];
    const float* mask     = (const float*)d_in[1];
    const float* ln_in_w  = (const float*)d_in[2];
    const float* ln_in_b  = (const float*)d_in[3];
    const float* w_ap     = (const float*)d_in[4];
    const float* b_ap     = (const float*)d_in[5];
    const float* w_ag     = (const float*)d_in[6];
    const float* b_ag     = (const float*)d_in[7];
    const float* w_bp     = (const float*)d_in[8];
    const float* b_bp     = (const float*)d_in[9];
    const float* w_bg     = (const float*)d_in[10];
    const float* b_bg     = (const float*)d_in[11];
    const float* ln_out_w = (const float*)d_in[12];
    const float* ln_out_b = (const float*)d_in[13];
    const float* w_o      = (const float*)d_in[14];
    const float* b_o      = (const float*)d_in[15];
    const float* w_g      = (const float*)d_in[16];
    const float* b_g      = (const float*)d_in[17];

    char* ws = (char*)d_ws;
    const size_t BUF = (size_t)NN * 128 * 2;      // 64 MB per f16 buffer
    unsigned short* a_t   = (unsigned short*)(ws);
    unsigned short* b_t   = (unsigned short*)(ws + BUF);
    unsigned short* zln   = (unsigned short*)(ws + 2*BUF);
    unsigned short* x_t   = (unsigned short*)(ws + 3*BUF);
    unsigned short* Wfrag = (unsigned short*)(ws + 4*BUF);
    unsigned short* Wo_t  = (unsigned short*)(ws + 4*BUF + (size_t)10240*8*2);

    k0_prep<<<104, 256, 0, stream>>>(w_ag, w_ap, w_bg, w_bp, w_g, w_o, Wfrag, Wo_t);
    k1a_ln<<<NN/64, 256, 0, stream>>>(z, ln_in_w, ln_in_b, zln);
    k1b_proj<<<NN/64, 256, 0, stream>>>(zln, mask, Wfrag,
                                        b_ag, b_ap, b_bg, b_bp, a_t, b_t);
    k2_einsum<<<dim3(16, 128), 256, 0, stream>>>(a_t, b_t, x_t);
    k3_out<<<NN/128, 256, 0, stream>>>(x_t, zln, Wfrag, Wo_t, ln_out_w, ln_out_b,
                                       b_o, b_g, (float*)d_out);
}